// Round 14
// baseline (223.206 us; speedup 1.0000x reference)
//
#include <hip/hip_runtime.h>
#include <hip/hip_bf16.h>
#include <stdint.h>

// ---------- common types/helpers ----------
typedef unsigned short u16;
typedef __attribute__((ext_vector_type(8))) short s16x8;   // 8 bf16 (4 VGPRs) MFMA operand
typedef __attribute__((ext_vector_type(4))) short s16x4;   // 4 bf16 (2 VGPRs)
typedef __attribute__((ext_vector_type(4))) float f32x4;   // MFMA accumulator

__device__ __forceinline__ u16 f2bf(float f){              // RNE f32->bf16
  uint32_t u = __builtin_bit_cast(uint32_t, f);
  u += 0x7FFFu + ((u >> 16) & 1u);
  return (u16)(u >> 16);
}
__device__ __forceinline__ float bf2f(u16 h){
  uint32_t u = ((uint32_t)h) << 16;
  return __builtin_bit_cast(float, u);
}
// async global->LDS, 16B per lane. LDS dest is wave-uniform base (+lane*16 by HW).
__device__ __forceinline__ void gl_lds16(const void* g, void* l){
  __builtin_amdgcn_global_load_lds((__attribute__((address_space(1))) void*)g,
                                   (__attribute__((address_space(3))) void*)l,
                                   16, 0, 0);
}

// Problem constants
#define MROWS 16384      // B*L
#define DMODEL 1024
#define NQKV 3072
#define NSEGS 64         // B * (L/SEG)
// ws offsets (bytes)
#define O_XB    0u
#define O_WQKV  33554432u
#define O_WO    39845888u
#define O_BQKV  41943040u
#define O_QKV   41955328u
#define O_VT    142618624u
#define O_GOUT  176173056u
#define O_GPR   176435200u

// ---------- kernel 1: pack f32 -> bf16 (x, Wq|Wk|Wv, Wo) + bias concat ----------
__global__ __launch_bounds__(256) void pack_kernel(
    const float* __restrict__ x,
    const float* __restrict__ wq, const float* __restrict__ wk,
    const float* __restrict__ wv, const float* __restrict__ wo,
    const float* __restrict__ bq, const float* __restrict__ bk, const float* __restrict__ bv,
    u16* __restrict__ xb, u16* __restrict__ wqkvb, u16* __restrict__ wob,
    float* __restrict__ bqkv)
{
  const int stride = gridDim.x * 256;
  const int gid = blockIdx.x * 256 + threadIdx.x;
  if(gid < 3072)
    bqkv[gid] = (gid < 1024) ? bq[gid] : (gid < 2048 ? bk[gid - 1024] : bv[gid - 2048]);
  for(int q = gid; q < 4194304; q += stride){          // x: 16.7M elems
    float4 v = *(const float4*)(x + (size_t)q * 4);
    ushort4 o; o.x = f2bf(v.x); o.y = f2bf(v.y); o.z = f2bf(v.z); o.w = f2bf(v.w);
    *(ushort4*)(xb + (size_t)q * 4) = o;
  }
  for(int q = gid; q < 786432; q += stride){           // Wqkv: 3M elems
    int elem = q << 2;
    int m = elem >> 20;                                // 0=Wq 1=Wk 2=Wv (1024 rows each)
    const float* s = (m == 0) ? wq : (m == 1 ? wk : wv);
    float4 v = *(const float4*)(s + (elem & 1048575));
    ushort4 o; o.x = f2bf(v.x); o.y = f2bf(v.y); o.z = f2bf(v.z); o.w = f2bf(v.w);
    *(ushort4*)(wqkvb + elem) = o;
  }
  for(int q = gid; q < 262144; q += stride){           // Wo: 1M elems
    float4 v = *(const float4*)(wo + (size_t)q * 4);
    ushort4 o; o.x = f2bf(v.x); o.y = f2bf(v.y); o.z = f2bf(v.z); o.w = f2bf(v.w);
    *(ushort4*)(wob + (size_t)q * 4) = o;
  }
}

// ---------- kernel 2: QKV GEMM on the gemm128 structure (2 blocks/CU) ----------
// 256x128 tile, 8 waves (2Mx4N, 128x32 per wave), BK=32, 3 LDS bufs (72KB) ->
// 2 blocks/CU: inter-block TLP hides the per-tile vmcnt+barrier stall that caps
// the 1-block/CU gemm256 at ~820 TF (out-proj on this structure: ~930 TF).
// Q/K blocks (bcol<2048): bf16 C-write. V blocks: per-wave LDS transpose
// (32e x 128t = 8KB/wave, 64KB total) -> coalesced Vt write; qkv V-region dead.
__global__ __launch_bounds__(512, 4) void gemm_qkv_kernel(
    const u16* __restrict__ A, const u16* __restrict__ Bt,
    const float* __restrict__ bias, u16* __restrict__ Cv, u16* __restrict__ Vt)
{
  __shared__ char sm[73728];    // buf j at j*24576: A 256x32 (16KB) + B 128x32 (8KB)
  const int tid = threadIdx.x;
  const int wv = tid >> 6, lane = tid & 63;
  const int l15 = lane & 15, l4 = lane >> 4;
  const int wr = wv >> 2, wc = wv & 3;

  const int nwg = (int)gridDim.x;             // 1536, %8==0
  int bid = (int)blockIdx.x;
  bid = (bid & 7) * (nwg >> 3) + (bid >> 3);  // XCD swizzle: 8 full A-rows per XCD
  const int brow = (bid / 24) << 8, bcol = (bid % 24) << 7;

  int offA[8], offB[2];
#pragma unroll
  for(int m = 0; m < 8; ++m){
    int row = wr * 128 + m * 16 + l15;
    offA[m] = row * 64 + ((l4 ^ ((row >> 1) & 3)) << 4);
  }
#pragma unroll
  for(int n = 0; n < 2; ++n){
    int row = wc * 32 + n * 16 + l15;
    offB[n] = 16384 + row * 64 + ((l4 ^ ((row >> 1) & 3)) << 4);
  }

  const u16* srcA[2]; const u16* srcB; int dstOff[2];
#pragma unroll
  for(int r = 0; r < 2; ++r){
    int off = r * 8192 + tid * 16;
    int row = off >> 6, g = (off >> 4) & 3;
    int gs = g ^ ((row >> 1) & 3);
    srcA[r] = A + (size_t)(brow + row) * DMODEL + gs * 8;
    dstOff[r] = r * 8192 + wv * 1024;
  }
  {
    int off = tid * 16;
    int row = off >> 6, g = (off >> 4) & 3;
    int gs = g ^ ((row >> 1) & 3);
    srcB = Bt + (size_t)(bcol + row) * DMODEL + gs * 8;
  }

#define STAGEQ(kt_, buf_) do{                                     \
    char* base_ = sm + (buf_) * 24576;                            \
    const int ko_ = (kt_) << 5;                                   \
    gl_lds16(srcA[0] + ko_, base_ + dstOff[0]);                   \
    gl_lds16(srcA[1] + ko_, base_ + dstOff[1]);                   \
    gl_lds16(srcB + ko_, base_ + 16384 + wv * 1024);              \
  }while(0)

  const f32x4 fz = {0.f, 0.f, 0.f, 0.f};
  f32x4 acc[8][2];
#pragma unroll
  for(int m = 0; m < 8; ++m)
#pragma unroll
    for(int n = 0; n < 2; ++n) acc[m][n] = fz;

  const int nkt = DMODEL >> 5;    // 32
  STAGEQ(0, 0); STAGEQ(1, 1);
  int cur = 0;
  for(int kt = 0; kt < nkt; ++kt){
    if(kt + 1 < nkt) asm volatile("s_waitcnt vmcnt(3)" ::: "memory");
    else             asm volatile("s_waitcnt vmcnt(0)" ::: "memory");
    __builtin_amdgcn_s_barrier();
    asm volatile("" ::: "memory");
    if(kt + 2 < nkt){
      int nb = cur + 2; if(nb >= 3) nb -= 3;
      STAGEQ(kt + 2, nb);
    }
    char* cb = sm + cur * 24576;
    s16x8 b[2], a[4];
#pragma unroll
    for(int n = 0; n < 2; ++n) b[n] = *(const s16x8*)(cb + offB[n]);
#pragma unroll
    for(int m = 0; m < 4; ++m) a[m] = *(const s16x8*)(cb + offA[m]);
    __builtin_amdgcn_s_setprio(1);
#pragma unroll
    for(int m = 0; m < 4; ++m)
#pragma unroll
      for(int n = 0; n < 2; ++n)
        acc[m][n] = __builtin_amdgcn_mfma_f32_16x16x32_bf16(a[m], b[n], acc[m][n], 0, 0, 0);
    __builtin_amdgcn_s_setprio(0);
#pragma unroll
    for(int m = 0; m < 4; ++m) a[m] = *(const s16x8*)(cb + offA[m + 4]);
    __builtin_amdgcn_s_setprio(1);
#pragma unroll
    for(int m = 0; m < 4; ++m)
#pragma unroll
      for(int n = 0; n < 2; ++n)
        acc[m + 4][n] = __builtin_amdgcn_mfma_f32_16x16x32_bf16(a[m], b[n], acc[m + 4][n], 0, 0, 0);
    __builtin_amdgcn_s_setprio(0);
    if(++cur == 3) cur = 0;
  }
#undef STAGEQ

  float bvv[2];
#pragma unroll
  for(int n = 0; n < 2; ++n) bvv[n] = bias[bcol + wc * 32 + n * 16 + l15];

  if(bcol < 2048){
    // Q/K blocks: plain bf16 C-write into qkv
#pragma unroll
    for(int m = 0; m < 8; ++m)
#pragma unroll
      for(int n = 0; n < 2; ++n)
#pragma unroll
        for(int r = 0; r < 4; ++r){
          const int row = brow + wr * 128 + m * 16 + (l4 << 2) + r;
          const int col = bcol + wc * 32 + n * 16 + l15;
          Cv[(size_t)row * NQKV + col] = f2bf(acc[m][n][r] + bvv[n]);
        }
  } else {
    // V blocks: transpose-only epilogue (qkv V-region dead; gpv/attn read Vt).
    // M-tile == SEG == 256, so brow is a whole segment. Wave chunk: 32e x 128t.
    __syncthreads();                       // all main-loop LDS reads retired
    char* wbase = sm + wv * 8192;          // 32 eL rows x 256B (128t x 2B)
    const int swzW = (l15 & 7) << 4;       // eL&7 == l15&7
#pragma unroll
    for(int n = 0; n < 2; ++n)
#pragma unroll
      for(int m = 0; m < 8; ++m){
        s16x4 pk;
#pragma unroll
        for(int r = 0; r < 4; ++r) pk[r] = (short)f2bf(acc[m][n][r] + bvv[n]);
        const int eL = n * 16 + l15;                 // 0..31
        const int tB = (m * 16 + (l4 << 2)) * 2;     // byte offset in 256B row
        *(s16x4*)(wbase + ((eL * 256 + tB) ^ swzW)) = pk;
      }
    asm volatile("s_waitcnt lgkmcnt(0)" ::: "memory");   // wave-local data only
    const int seg = brow >> 8;
    const int e0  = bcol - 2048 + wc * 32;
    const int c = lane & 15, eSub = lane >> 4;
#pragma unroll
    for(int i = 0; i < 8; ++i){
      const int eL = i * 4 + eSub;
      s16x8 vvv = *(const s16x8*)(wbase + ((eL * 256 + c * 16) ^ ((eL & 7) << 4)));
      *(s16x8*)(Vt + (size_t)seg * 262144 + (size_t)(e0 + eL) * 256 + wr * 128 + c * 8) = vvv;
    }
  }
}

// ---------- kernel 2b: 256x128-tile GEMM, 3 LDS bufs (72KB) -> 2 blocks/CU ----------
__global__ __launch_bounds__(512, 4) void gemm128_kernel(
    const u16* __restrict__ A, const u16* __restrict__ Bt,
    const float* __restrict__ bias, float* __restrict__ C,
    const int K, const int ldc, const int ncb)
{
  __shared__ char sm[73728];    // buf j at j*24576: A 256x32 (16KB) + B 128x32 (8KB)
  const int tid = threadIdx.x;
  const int wv = tid >> 6, lane = tid & 63;
  const int l15 = lane & 15, l4 = lane >> 4;
  const int wr = wv >> 2, wc = wv & 3;

  const int nwg = (int)gridDim.x;
  int bid = (int)blockIdx.x;
  bid = (bid & 7) * (nwg >> 3) + (bid >> 3);
  const int brow = (bid / ncb) << 8, bcol = (bid % ncb) << 7;

  int offA[8], offB[2];
#pragma unroll
  for(int m = 0; m < 8; ++m){
    int row = wr * 128 + m * 16 + l15;
    offA[m] = row * 64 + ((l4 ^ ((row >> 1) & 3)) << 4);
  }
#pragma unroll
  for(int n = 0; n < 2; ++n){
    int row = wc * 32 + n * 16 + l15;
    offB[n] = 16384 + row * 64 + ((l4 ^ ((row >> 1) & 3)) << 4);
  }

  const u16* srcA[2]; const u16* srcB; int dstOff[2];
#pragma unroll
  for(int r = 0; r < 2; ++r){
    int off = r * 8192 + tid * 16;
    int row = off >> 6, g = (off >> 4) & 3;
    int gs = g ^ ((row >> 1) & 3);
    srcA[r] = A + (size_t)(brow + row) * K + gs * 8;
    dstOff[r] = r * 8192 + wv * 1024;
  }
  {
    int off = tid * 16;
    int row = off >> 6, g = (off >> 4) & 3;
    int gs = g ^ ((row >> 1) & 3);
    srcB = Bt + (size_t)(bcol + row) * K + gs * 8;
  }

#define STAGE128(kt_, buf_) do{                                   \
    char* base_ = sm + (buf_) * 24576;                            \
    const int ko_ = (kt_) << 5;                                   \
    gl_lds16(srcA[0] + ko_, base_ + dstOff[0]);                   \
    gl_lds16(srcA[1] + ko_, base_ + dstOff[1]);                   \
    gl_lds16(srcB + ko_, base_ + 16384 + wv * 1024);              \
  }while(0)

  const f32x4 fz = {0.f, 0.f, 0.f, 0.f};
  f32x4 acc[8][2];
#pragma unroll
  for(int m = 0; m < 8; ++m)
#pragma unroll
    for(int n = 0; n < 2; ++n) acc[m][n] = fz;

  const int nkt = K >> 5;
  STAGE128(0, 0); STAGE128(1, 1);
  int cur = 0;
  for(int kt = 0; kt < nkt; ++kt){
    if(kt + 1 < nkt) asm volatile("s_waitcnt vmcnt(3)" ::: "memory");
    else             asm volatile("s_waitcnt vmcnt(0)" ::: "memory");
    __builtin_amdgcn_s_barrier();
    asm volatile("" ::: "memory");
    if(kt + 2 < nkt){
      int nb = cur + 2; if(nb >= 3) nb -= 3;
      STAGE128(kt + 2, nb);
    }
    char* cb = sm + cur * 24576;
    s16x8 b[2], a[4];
#pragma unroll
    for(int n = 0; n < 2; ++n) b[n] = *(const s16x8*)(cb + offB[n]);
#pragma unroll
    for(int m = 0; m < 4; ++m) a[m] = *(const s16x8*)(cb + offA[m]);
    __builtin_amdgcn_s_setprio(1);
#pragma unroll
    for(int m = 0; m < 4; ++m)
#pragma unroll
      for(int n = 0; n < 2; ++n)
        acc[m][n] = __builtin_amdgcn_mfma_f32_16x16x32_bf16(a[m], b[n], acc[m][n], 0, 0, 0);
    __builtin_amdgcn_s_setprio(0);
#pragma unroll
    for(int m = 0; m < 4; ++m) a[m] = *(const s16x8*)(cb + offA[m + 4]);
    __builtin_amdgcn_s_setprio(1);
#pragma unroll
    for(int m = 0; m < 4; ++m)
#pragma unroll
      for(int n = 0; n < 2; ++n)
        acc[m + 4][n] = __builtin_amdgcn_mfma_f32_16x16x32_bf16(a[m], b[n], acc[m + 4][n], 0, 0, 0);
    __builtin_amdgcn_s_setprio(0);
    if(++cur == 3) cur = 0;
  }
#undef STAGE128

  float bvv[2];
#pragma unroll
  for(int n = 0; n < 2; ++n) bvv[n] = bias[bcol + wc * 32 + n * 16 + l15];
#pragma unroll
  for(int m = 0; m < 8; ++m)
#pragma unroll
    for(int n = 0; n < 2; ++n)
#pragma unroll
      for(int r = 0; r < 4; ++r){
        const int row = brow + wr * 128 + m * 16 + (l4 << 2) + r;
        const int col = bcol + wc * 32 + n * 16 + l15;
        C[(size_t)row * ldc + col] = acc[m][n][r] + bvv[n];
      }
}

// ---------- kernel 4a: global attention scores (parallel: 64 blocks) ----------
__global__ __launch_bounds__(256) void gscore_kernel(
    const u16* __restrict__ QKV, float* __restrict__ gpr)
{
  __shared__ float sc[16];
  const int b = blockIdx.x >> 4, i = blockIdx.x & 15;
  const int tid = threadIdx.x;
  const int j = tid >> 4, slice = tid & 15;
  const u16* qp = QKV + (size_t)(b * 16 + i) * 256 * NQKV + slice * 64;
  const u16* kp = QKV + (size_t)(b * 16 + j) * 256 * NQKV + 1024 + slice * 64;
  float acc = 0.f;
#pragma unroll
  for(int c = 0; c < 8; ++c){
    s16x8 qv = *(const s16x8*)(qp + c * 8);
    s16x8 kv = *(const s16x8*)(kp + c * 8);
#pragma unroll
    for(int e = 0; e < 8; ++e) acc += bf2f((u16)qv[e]) * bf2f((u16)kv[e]);
  }
#pragma unroll
  for(int off = 8; off >= 1; off >>= 1) acc += __shfl_xor(acc, off, 64);
  if(slice == 0) sc[j] = acc * 0.125f;
  __syncthreads();
  if(tid < 16){
    float v = sc[tid];
    float m = v;
#pragma unroll
    for(int off = 8; off >= 1; off >>= 1) m = fmaxf(m, __shfl_xor(m, off, 64));
    float p = __expf(v - m);
    float s = p;
#pragma unroll
    for(int off = 8; off >= 1; off >>= 1) s += __shfl_xor(s, off, 64);
    gpr[(size_t)b * 256 + i * 16 + tid] = p / s;
  }
}

// ---------- kernel 4b: global attention PV (reads V from Vt; 64 blocks) ----------
__global__ __launch_bounds__(256) void gpv_kernel(
    const u16* __restrict__ Vt, const float* __restrict__ gpr,
    float* __restrict__ gout)
{
  __shared__ float spr[256];
  const int b = blockIdx.x >> 4, ch = blockIdx.x & 15;
  const int tid = threadIdx.x;
  spr[tid] = gpr[(size_t)b * 256 + tid];
  __syncthreads();
  const int e = (ch << 6) + (tid & 63);
  const int ng = tid >> 6;
  const u16* vp = Vt + (size_t)(b * 16) * 262144 + (size_t)e * 256;
  float o0 = 0.f, o1 = 0.f, o2 = 0.f, o3 = 0.f;
#pragma unroll
  for(int m = 0; m < 16; ++m){
    float v = bf2f(vp[(size_t)m * 262144]);
    o0 += spr[(ng * 4 + 0) * 16 + m] * v;
    o1 += spr[(ng * 4 + 1) * 16 + m] * v;
    o2 += spr[(ng * 4 + 2) * 16 + m] * v;
    o3 += spr[(ng * 4 + 3) * 16 + m] * v;
  }
  gout[((size_t)b * 16 + ng * 4 + 0) * 1024 + e] = o0;
  gout[((size_t)b * 16 + ng * 4 + 1) * 1024 + e] = o1;
  gout[((size_t)b * 16 + ng * 4 + 2) * 1024 + e] = o2;
  gout[((size_t)b * 16 + ng * 4 + 3) * 1024 + e] = o3;
}

// ---------- kernel 5: fused local attention (v3: mini-GEMM pipeline, R11) ----------
__global__ __launch_bounds__(512, 2) void attn_local_kernel(
    const u16* __restrict__ QKV, const u16* __restrict__ Vt,
    const float* __restrict__ gout, u16* __restrict__ AO)
{
  __shared__ char sm[131072];
  float* smax = (float*)(sm + 32768);
  float* ssum = (float*)(sm + 33792);
  const int tid = threadIdx.x;
  const int wv = tid >> 6, lane = tid & 63;
  const int l15 = lane & 15, l4 = lane >> 4;
  const int wr = wv >> 2, wc = wv & 3;
  int bid = (int)blockIdx.x;
  bid = (bid & 7) * 32 + (bid >> 3);
  const int seg = bid >> 2, rt = bid & 3;
  const int r0 = rt << 6;
  const size_t segQ = (size_t)seg * 256 * NQKV;

  const int offq = wv * 1024 + lane * 16;
  const int dstQ = wv * 1024;
  const int qrow = offq >> 7;
  const int qgs  = ((offq >> 4) & 7) ^ (qrow & 7);
  const u16* qsrc = QKV + segQ + (size_t)(r0 + qrow) * NQKV + qgs * 8;
  const u16* ksrc[4];
  const u16* vsrc[4];
#pragma unroll
  for(int c = 0; c < 4; ++c){
    int off = c * 8192 + offq;
    int row = off >> 7;
    int gs  = ((off >> 4) & 7) ^ (row & 7);
    ksrc[c] = QKV + segQ + (size_t)row * NQKV + 1024 + gs * 8;
    vsrc[c] = Vt + (size_t)seg * 262144 + (size_t)row * 256 + gs * 8;
  }

#define STAGE_P1(d0_, base_) do{                                        \
    gl_lds16(qsrc + (d0_), sm + (base_) + dstQ);                        \
    _Pragma("unroll")                                                   \
    for(int c_ = 0; c_ < 4; ++c_)                                       \
      gl_lds16(ksrc[c_] + (d0_), sm + (base_) + 8192 + c_ * 8192 + dstQ); \
  }while(0)
#define STAGE_V(j_, vb_) do{                                            \
    const int vo_ = ((j_) >> 2) * 65536 + ((j_) & 3) * 64;              \
    _Pragma("unroll")                                                   \
    for(int c_ = 0; c_ < 4; ++c_)                                       \
      gl_lds16(vsrc[c_] + vo_, sm + 32768 + (vb_) * 32768 + c_ * 8192 + dstQ); \
  }while(0)

  int aOff[2][2], bOff[4][2];
#pragma unroll
  for(int m = 0; m < 2; ++m){
    int row = wr * 32 + m * 16 + l15;
#pragma unroll
    for(int kk = 0; kk < 2; ++kk)
      aOff[m][kk] = row * 128 + ((kk * 64 + l4 * 16) ^ ((row & 7) << 4));
  }
#pragma unroll
  for(int n = 0; n < 4; ++n){
    int row = wc * 64 + n * 16 + l15;
#pragma unroll
    for(int kk = 0; kk < 2; ++kk)
      bOff[n][kk] = 8192 + row * 128 + ((kk * 64 + l4 * 16) ^ ((row & 7) << 4));
  }

  const f32x4 fz = {0.f, 0.f, 0.f, 0.f};
  f32x4 acc1[2][4];
#pragma unroll
  for(int m = 0; m < 2; ++m)
#pragma unroll
    for(int n = 0; n < 4; ++n) acc1[m][n] = fz;

  STAGE_P1(0, 0); STAGE_P1(64, 40960);
  asm volatile("s_waitcnt vmcnt(5)" ::: "memory");
  __builtin_amdgcn_s_barrier();
  asm volatile("" ::: "memory");
  int cur = 0;
  for(int dt = 0; dt < 16; ++dt){
    const int base = cur * 40960;
    if(dt + 2 < 16){
      int nb = cur + 2; if(nb >= 3) nb -= 3;
      STAGE_P1((dt + 2) << 6, nb * 40960);
    }
    s16x8 a[2][2], b[4][2];
#pragma unroll
    for(int m = 0; m < 2; ++m)
#pragma unroll
      for(int kk = 0; kk < 2; ++kk) a[m][kk] = *(const s16x8*)(sm + base + aOff[m][kk]);
#pragma unroll
    for(int n = 0; n < 4; ++n)
#pragma unroll
      for(int kk = 0; kk < 2; ++kk) b[n][kk] = *(const s16x8*)(sm + base + bOff[n][kk]);
    __builtin_amdgcn_s_setprio(1);
#pragma unroll
    for(int kk = 0; kk < 2; ++kk)
#pragma unroll
      for(int m = 0; m < 2; ++m)
#pragma unroll
        for(int n = 0; n < 4; ++n)
          acc1[m][n] = __builtin_amdgcn_mfma_f32_16x16x32_bf16(a[m][kk], b[n][kk], acc1[m][n], 0, 0, 0);
    __builtin_amdgcn_s_setprio(0);
    if(dt + 2 < 16) asm volatile("s_waitcnt vmcnt(5) lgkmcnt(0)" ::: "memory");
    else            asm volatile("s_waitcnt vmcnt(0) lgkmcnt(0)" ::: "memory");
    __builtin_amdgcn_s_barrier();
    asm volatile("" ::: "memory");
    if(++cur == 3) cur = 0;
  }

  const float CE = 0.18033688011112042f;   // SCALE * log2(e)
#pragma unroll
  for(int m = 0; m < 2; ++m)
#pragma unroll
    for(int r = 0; r < 4; ++r){
      float v = -1e30f;
#pragma unroll
      for(int n = 0; n < 4; ++n) v = fmaxf(v, acc1[m][n][r]);
#pragma unroll
      for(int off = 8; off >= 1; off >>= 1) v = fmaxf(v, __shfl_xor(v, off, 64));
      if(l15 == 0) smax[wc * 64 + wr * 32 + m * 16 + (l4 << 2) + r] = v;
    }
  asm volatile("s_waitcnt lgkmcnt(0)" ::: "memory");
  __builtin_amdgcn_s_barrier();
  asm volatile("" ::: "memory");
#pragma unroll
  for(int m = 0; m < 2; ++m)
#pragma unroll
    for(int r = 0; r < 4; ++r){
      const int idx = wr * 32 + m * 16 + (l4 << 2) + r;
      const float g = fmaxf(fmaxf(smax[idx], smax[64 + idx]),
                            fmaxf(smax[128 + idx], smax[192 + idx]));
      float s = 0.f;
#pragma unroll
      for(int n = 0; n < 4; ++n){
        float p = exp2f((acc1[m][n][r] - g) * CE);
        acc1[m][n][r] = p;
        s += p;
      }
#pragma unroll
      for(int off = 8; off >= 1; off >>= 1) s += __shfl_xor(s, off, 64);
      if(l15 == 0) ssum[wc * 64 + idx] = s;
    }
  asm volatile("s_waitcnt lgkmcnt(0)" ::: "memory");
  __builtin_amdgcn_s_barrier();
  asm volatile("" ::: "memory");
  float inv2[2][4];
#pragma unroll
  for(int m = 0; m < 2; ++m)
#pragma unroll
    for(int r = 0; r < 4; ++r){
      const int idx = wr * 32 + m * 16 + (l4 << 2) + r;
      inv2[m][r] = 1.f / (ssum[idx] + ssum[64 + idx] + ssum[128 + idx] + ssum[192 + idx]);
    }
#pragma unroll
  for(int m = 0; m < 2; ++m)
#pragma unroll
    for(int n = 0; n < 4; ++n)
#pragma unroll
      for(int r = 0; r < 4; ++r){
        const int rr = wr * 32 + m * 16 + (l4 << 2) + r;
        const int t  = wc * 64 + n * 16 + l15;
        *(u16*)(sm + rr * 512 + ((t << 1) ^ ((rr & 7) << 4))) = f2bf(acc1[m][n][r] * inv2[m][r]);
      }
  asm volatile("s_waitcnt lgkmcnt(0)" ::: "memory");
  __builtin_amdgcn_s_barrier();
  asm volatile("" ::: "memory");

  int prow[2], pswz[2];
#pragma unroll
  for(int m = 0; m < 2; ++m){
    int row = wr * 32 + m * 16 + l15;
    prow[m] = row * 512;
    pswz[m] = (row & 7) << 4;
  }
  int vOff[4][2];
#pragma unroll
  for(int n = 0; n < 4; ++n){
    int row = wc * 64 + n * 16 + l15;
#pragma unroll
    for(int kk = 0; kk < 2; ++kk)
      vOff[n][kk] = row * 128 + ((kk * 64 + l4 * 16) ^ ((row & 7) << 4));
  }

  STAGE_V(0, 0); STAGE_V(1, 1);
  asm volatile("s_waitcnt vmcnt(4)" ::: "memory");
  __builtin_amdgcn_s_barrier();
  asm volatile("" ::: "memory");
  f32x4 acc2[2][4];
  int cv = 0;
  for(int j = 0; j < 16; ++j){
    const int ts = j & 3, ns = j >> 2;
    if(ts == 0){
#pragma unroll
      for(int m = 0; m < 2; ++m)
#pragma unroll
        for(int n = 0; n < 4; ++n) acc2[m][n] = fz;
    }
    if(j + 2 < 16){
      int nb = cv + 2; if(nb >= 3) nb -= 3;
      STAGE_V(j + 2, nb);
    }
    char* vbase = sm + 32768 + cv * 32768;
    s16x8 a[2][2], b[4][2];
#pragma unroll
    for(int m = 0; m < 2; ++m)
#pragma unroll
      for(int kk = 0; kk < 2; ++kk)
        a[m][kk] = *(const s16x8*)(sm + prow[m] + (((ts << 7) + (kk << 6) + (l4 << 4)) ^ pswz[m]));
#pragma unroll
    for(int n = 0; n < 4; ++n)
#pragma unroll
      for(int kk = 0; kk < 2; ++kk) b[n][kk] = *(const s16x8*)(vbase + vOff[n][kk]);
    __builtin_amdgcn_s_setprio(1);
#pragma unroll
    for(int kk = 0; kk < 2; ++kk)
#pragma unroll
      for(int m = 0; m < 2; ++m)
#pragma unroll
        for(int n = 0; n < 4; ++n)
          acc2[m][n] = __builtin_amdgcn_mfma_f32_16x16x32_bf16(a[m][kk], b[n][kk], acc2[m][n], 0, 0, 0);
    __builtin_amdgcn_s_setprio(0);
    if(j + 2 < 16) asm volatile("s_waitcnt vmcnt(4) lgkmcnt(0)" ::: "memory");
    else           asm volatile("s_waitcnt vmcnt(0) lgkmcnt(0)" ::: "memory");
    __builtin_amdgcn_s_barrier();
    asm volatile("" ::: "memory");
    if(++cv == 3) cv = 0;

    if(ts == 3){
      float gv[4];
#pragma unroll
      for(int n = 0; n < 4; ++n)
        gv[n] = gout[(size_t)seg * 1024 + ns * 256 + wc * 64 + n * 16 + l15];
#pragma unroll
      for(int m = 0; m < 2; ++m)
#pragma unroll
        for(int n = 0; n < 4; ++n)
#pragma unroll
          for(int r = 0; r < 4; ++r){
            const int row = r0 + wr * 32 + m * 16 + (l4 << 2) + r;
            const int e   = ns * 256 + wc * 64 + n * 16 + l15;
            AO[((size_t)seg * 256 + row) * 1024 + e] = f2bf(acc2[m][n][r] + gv[n]);
          }
    }
  }
#undef STAGE_P1
#undef STAGE_V
}

// ---------- launch ----------
extern "C" void kernel_launch(void* const* d_in, const int* in_sizes, int n_in,
                              void* d_out, int out_size, void* d_ws, size_t ws_size,
                              hipStream_t stream)
{
  const float* x  = (const float*)d_in[0];
  const float* Wq = (const float*)d_in[1];
  const float* bq = (const float*)d_in[2];
  const float* Wk = (const float*)d_in[3];
  const float* bk = (const float*)d_in[4];
  const float* Wv = (const float*)d_in[5];
  const float* bv = (const float*)d_in[6];
  const float* Wo = (const float*)d_in[7];
  const float* bo = (const float*)d_in[8];

  char* ws = (char*)d_ws;
  u16*   xb    = (u16*)(ws + O_XB);
  u16*   wqkvb = (u16*)(ws + O_WQKV);
  u16*   wob   = (u16*)(ws + O_WO);
  float* bqkv  = (float*)(ws + O_BQKV);
  u16*   qkv   = (u16*)(ws + O_QKV);
  u16*   vt    = (u16*)(ws + O_VT);
  float* gout  = (float*)(ws + O_GOUT);
  float* gpr   = (float*)(ws + O_GPR);
  u16*   ao    = xb;   // alias: xb dead after QKV GEMM

  pack_kernel<<<4096, 256, 0, stream>>>(x, Wq, Wk, Wv, Wo, bq, bk, bv, xb, wqkvb, wob, bqkv);
  gemm_qkv_kernel<<<dim3((NQKV / 128) * (MROWS / 256)), 512, 0, stream>>>(
      xb, wqkvb, bqkv, qkv, vt);
  gscore_kernel<<<64, 256, 0, stream>>>(qkv, gpr);
  gpv_kernel<<<64, 256, 0, stream>>>(vt, gpr, gout);
  attn_local_kernel<<<256, 512, 0, stream>>>(qkv, vt, gout, ao);
  gemm128_kernel<<<dim3((DMODEL / 128) * (MROWS / 256)), 512, 0, stream>>>(
      ao, wob, bo, (float*)d_out, DMODEL, DMODEL, DMODEL / 128);
}

// Round 15
// 212.021 us; speedup vs baseline: 1.0528x; 1.0528x over previous
//
#include <hip/hip_runtime.h>
#include <hip/hip_bf16.h>
#include <stdint.h>

// ---------- common types/helpers ----------
typedef unsigned short u16;
typedef __attribute__((ext_vector_type(8))) short s16x8;   // 8 bf16 (4 VGPRs) MFMA operand
typedef __attribute__((ext_vector_type(4))) short s16x4;   // 4 bf16 (2 VGPRs)
typedef __attribute__((ext_vector_type(4))) float f32x4;   // MFMA accumulator

__device__ __forceinline__ u16 f2bf(float f){              // RNE f32->bf16
  uint32_t u = __builtin_bit_cast(uint32_t, f);
  u += 0x7FFFu + ((u >> 16) & 1u);
  return (u16)(u >> 16);
}
__device__ __forceinline__ float bf2f(u16 h){
  uint32_t u = ((uint32_t)h) << 16;
  return __builtin_bit_cast(float, u);
}
// async global->LDS, 16B per lane. LDS dest is wave-uniform base (+lane*16 by HW).
__device__ __forceinline__ void gl_lds16(const void* g, void* l){
  __builtin_amdgcn_global_load_lds((__attribute__((address_space(1))) void*)g,
                                   (__attribute__((address_space(3))) void*)l,
                                   16, 0, 0);
}

// Problem constants
#define MROWS 16384      // B*L
#define DMODEL 1024
#define NQKV 3072
#define NSEGS 64         // B * (L/SEG)
// ws offsets (bytes)
#define O_XB    0u
#define O_WQKV  33554432u
#define O_WO    39845888u
#define O_BQKV  41943040u
#define O_QKV   41955328u
#define O_VT    142618624u
#define O_GOUT  176173056u
#define O_GPR   176435200u

// ---------- kernel 1: pack f32 -> bf16 (x, Wq|Wk|Wv, Wo) + bias concat ----------
__global__ __launch_bounds__(256) void pack_kernel(
    const float* __restrict__ x,
    const float* __restrict__ wq, const float* __restrict__ wk,
    const float* __restrict__ wv, const float* __restrict__ wo,
    const float* __restrict__ bq, const float* __restrict__ bk, const float* __restrict__ bv,
    u16* __restrict__ xb, u16* __restrict__ wqkvb, u16* __restrict__ wob,
    float* __restrict__ bqkv)
{
  const int stride = gridDim.x * 256;
  const int gid = blockIdx.x * 256 + threadIdx.x;
  if(gid < 3072)
    bqkv[gid] = (gid < 1024) ? bq[gid] : (gid < 2048 ? bk[gid - 1024] : bv[gid - 2048]);
  for(int q = gid; q < 4194304; q += stride){          // x: 16.7M elems
    float4 v = *(const float4*)(x + (size_t)q * 4);
    ushort4 o; o.x = f2bf(v.x); o.y = f2bf(v.y); o.z = f2bf(v.z); o.w = f2bf(v.w);
    *(ushort4*)(xb + (size_t)q * 4) = o;
  }
  for(int q = gid; q < 786432; q += stride){           // Wqkv: 3M elems
    int elem = q << 2;
    int m = elem >> 20;                                // 0=Wq 1=Wk 2=Wv (1024 rows each)
    const float* s = (m == 0) ? wq : (m == 1 ? wk : wv);
    float4 v = *(const float4*)(s + (elem & 1048575));
    ushort4 o; o.x = f2bf(v.x); o.y = f2bf(v.y); o.z = f2bf(v.z); o.w = f2bf(v.w);
    *(ushort4*)(wqkvb + elem) = o;
  }
  for(int q = gid; q < 262144; q += stride){           // Wo: 1M elems
    float4 v = *(const float4*)(wo + (size_t)q * 4);
    ushort4 o; o.x = f2bf(v.x); o.y = f2bf(v.y); o.z = f2bf(v.z); o.w = f2bf(v.w);
    *(ushort4*)(wob + (size_t)q * 4) = o;
  }
}

// ---------- kernel 2: 256x256 pipelined QKV GEMM (R2 structure, proven) ----------
// Fused V-transpose epilogue: V-blocks (bcol>=2048) write ONLY Vt.
__global__ __launch_bounds__(512, 2) void gemm256_kernel(
    const u16* __restrict__ A, const u16* __restrict__ Bt,
    const float* __restrict__ bias, u16* __restrict__ Cv,
    u16* __restrict__ Vt, const int K, const int ldc, const int ncb)
{
  __shared__ char sm[131072];   // buf b at b*32768: A 256x32 bf16 (16KB) + B (16KB)
  const int tid = threadIdx.x;
  const int wv = tid >> 6, lane = tid & 63;
  const int l15 = lane & 15, l4 = lane >> 4;
  const int wr = wv >> 2, wc = wv & 3;

  const int nwg = (int)gridDim.x;
  int bid = (int)blockIdx.x;
  bid = (bid & 7) * (nwg >> 3) + (bid >> 3);
  const int brow = (bid / ncb) << 8, bcol = (bid % ncb) << 8;

  int offA[8], offB[4];
#pragma unroll
  for(int m = 0; m < 8; ++m){
    int row = wr * 128 + m * 16 + l15;
    offA[m] = row * 64 + ((l4 ^ ((row >> 1) & 3)) << 4);
  }
#pragma unroll
  for(int n = 0; n < 4; ++n){
    int row = wc * 64 + n * 16 + l15;
    offB[n] = 16384 + row * 64 + ((l4 ^ ((row >> 1) & 3)) << 4);
  }

  const u16* srcA[2]; const u16* srcB[2]; int dstOff[2];
#pragma unroll
  for(int r = 0; r < 2; ++r){
    int off = r * 8192 + tid * 16;
    int row = off >> 6, g = (off >> 4) & 3;
    int gs = g ^ ((row >> 1) & 3);
    srcA[r] = A  + (size_t)(brow + row) * K + gs * 8;
    srcB[r] = Bt + (size_t)(bcol + row) * K + gs * 8;
    dstOff[r] = r * 8192 + wv * 1024;
  }

#define STAGE256(kt_, buf_) do{                                   \
    char* base_ = sm + (buf_) * 32768;                            \
    const int ko_ = (kt_) << 5;                                   \
    gl_lds16(srcA[0] + ko_, base_ + dstOff[0]);                   \
    gl_lds16(srcA[1] + ko_, base_ + dstOff[1]);                   \
    gl_lds16(srcB[0] + ko_, base_ + 16384 + dstOff[0]);           \
    gl_lds16(srcB[1] + ko_, base_ + 16384 + dstOff[1]);           \
  }while(0)

  const f32x4 fz = {0.f, 0.f, 0.f, 0.f};
  f32x4 acc[8][4];
#pragma unroll
  for(int m = 0; m < 8; ++m)
#pragma unroll
    for(int n = 0; n < 4; ++n) acc[m][n] = fz;

  const int nkt = K >> 5;
  STAGE256(0, 0); STAGE256(1, 1); STAGE256(2, 2);

  for(int kt = 0; kt < nkt; ++kt){
    const int rem = nkt - 1 - kt;
    if(rem >= 2)      asm volatile("s_waitcnt vmcnt(8)" ::: "memory");
    else if(rem == 1) asm volatile("s_waitcnt vmcnt(4)" ::: "memory");
    else              asm volatile("s_waitcnt vmcnt(0)" ::: "memory");
    __builtin_amdgcn_s_barrier();
    asm volatile("" ::: "memory");
    if(kt + 3 < nkt) STAGE256(kt + 3, (kt + 3) & 3);

    char* cb = sm + (kt & 3) * 32768;
    s16x8 b[4], a[4];
#pragma unroll
    for(int n = 0; n < 4; ++n) b[n] = *(const s16x8*)(cb + offB[n]);
#pragma unroll
    for(int m = 0; m < 4; ++m) a[m] = *(const s16x8*)(cb + offA[m]);
    __builtin_amdgcn_s_setprio(1);
#pragma unroll
    for(int m = 0; m < 4; ++m)
#pragma unroll
      for(int n = 0; n < 4; ++n)
        acc[m][n] = __builtin_amdgcn_mfma_f32_16x16x32_bf16(a[m], b[n], acc[m][n], 0, 0, 0);
    __builtin_amdgcn_s_setprio(0);
#pragma unroll
    for(int m = 0; m < 4; ++m) a[m] = *(const s16x8*)(cb + offA[m + 4]);
    __builtin_amdgcn_s_setprio(1);
#pragma unroll
    for(int m = 0; m < 4; ++m)
#pragma unroll
      for(int n = 0; n < 4; ++n)
        acc[m + 4][n] = __builtin_amdgcn_mfma_f32_16x16x32_bf16(a[m], b[n], acc[m + 4][n], 0, 0, 0);
    __builtin_amdgcn_s_setprio(0);
  }
#undef STAGE256

  float bvv[4];
#pragma unroll
  for(int n = 0; n < 4; ++n) bvv[n] = bias[bcol + wc * 64 + n * 16 + l15];

  if(bcol < 2048){
#pragma unroll
    for(int m = 0; m < 8; ++m)
#pragma unroll
      for(int n = 0; n < 4; ++n)
#pragma unroll
        for(int r = 0; r < 4; ++r){
          const int row = brow + wr * 128 + m * 16 + (l4 << 2) + r;
          const int col = bcol + wc * 64 + n * 16 + l15;
          Cv[(size_t)row * ldc + col] = f2bf(acc[m][n][r] + bvv[n]);
        }
  } else {
    __syncthreads();                       // all main-loop LDS reads retired
    char* wbase = sm + wv * 16384;         // wave-private 64e x 128t x 2B
    const int swzW = (l15 & 7) << 4;
#pragma unroll
    for(int n = 0; n < 4; ++n)
#pragma unroll
      for(int m = 0; m < 8; ++m){
        s16x4 pk;
#pragma unroll
        for(int r = 0; r < 4; ++r) pk[r] = (short)f2bf(acc[m][n][r] + bvv[n]);
        const int eL = n * 16 + l15;
        const int tB = (m * 16 + (l4 << 2)) * 2;
        *(s16x4*)(wbase + ((eL * 256 + tB) ^ swzW)) = pk;
      }
    asm volatile("s_waitcnt lgkmcnt(0)" ::: "memory");
    const int seg = brow >> 8;
    const int e0  = bcol - 2048 + wc * 64;
    const int c = lane & 15, eSub = lane >> 4;
#pragma unroll
    for(int i = 0; i < 16; ++i){
      const int eL = i * 4 + eSub;
      s16x8 vvv = *(const s16x8*)(wbase + ((eL * 256 + c * 16) ^ ((eL & 7) << 4)));
      *(s16x8*)(Vt + (size_t)seg * 262144 + (size_t)(e0 + eL) * 256 + wr * 128 + c * 8) = vvv;
    }
  }
}

// ---------- kernel 2b: 256x128-tile GEMM, 3 LDS bufs (72KB) -> 2 blocks/CU ----------
__global__ __launch_bounds__(512, 4) void gemm128_kernel(
    const u16* __restrict__ A, const u16* __restrict__ Bt,
    const float* __restrict__ bias, float* __restrict__ C,
    const int K, const int ldc, const int ncb)
{
  __shared__ char sm[73728];    // buf j at j*24576: A 256x32 (16KB) + B 128x32 (8KB)
  const int tid = threadIdx.x;
  const int wv = tid >> 6, lane = tid & 63;
  const int l15 = lane & 15, l4 = lane >> 4;
  const int wr = wv >> 2, wc = wv & 3;

  const int nwg = (int)gridDim.x;
  int bid = (int)blockIdx.x;
  bid = (bid & 7) * (nwg >> 3) + (bid >> 3);
  const int brow = (bid / ncb) << 8, bcol = (bid % ncb) << 7;

  int offA[8], offB[2];
#pragma unroll
  for(int m = 0; m < 8; ++m){
    int row = wr * 128 + m * 16 + l15;
    offA[m] = row * 64 + ((l4 ^ ((row >> 1) & 3)) << 4);
  }
#pragma unroll
  for(int n = 0; n < 2; ++n){
    int row = wc * 32 + n * 16 + l15;
    offB[n] = 16384 + row * 64 + ((l4 ^ ((row >> 1) & 3)) << 4);
  }

  const u16* srcA[2]; const u16* srcB; int dstOff[2];
#pragma unroll
  for(int r = 0; r < 2; ++r){
    int off = r * 8192 + tid * 16;
    int row = off >> 6, g = (off >> 4) & 3;
    int gs = g ^ ((row >> 1) & 3);
    srcA[r] = A + (size_t)(brow + row) * K + gs * 8;
    dstOff[r] = r * 8192 + wv * 1024;
  }
  {
    int off = tid * 16;
    int row = off >> 6, g = (off >> 4) & 3;
    int gs = g ^ ((row >> 1) & 3);
    srcB = Bt + (size_t)(bcol + row) * K + gs * 8;
  }

#define STAGE128(kt_, buf_) do{                                   \
    char* base_ = sm + (buf_) * 24576;                            \
    const int ko_ = (kt_) << 5;                                   \
    gl_lds16(srcA[0] + ko_, base_ + dstOff[0]);                   \
    gl_lds16(srcA[1] + ko_, base_ + dstOff[1]);                   \
    gl_lds16(srcB + ko_, base_ + 16384 + wv * 1024);              \
  }while(0)

  const f32x4 fz = {0.f, 0.f, 0.f, 0.f};
  f32x4 acc[8][2];
#pragma unroll
  for(int m = 0; m < 8; ++m)
#pragma unroll
    for(int n = 0; n < 2; ++n) acc[m][n] = fz;

  const int nkt = K >> 5;
  STAGE128(0, 0); STAGE128(1, 1);
  int cur = 0;
  for(int kt = 0; kt < nkt; ++kt){
    if(kt + 1 < nkt) asm volatile("s_waitcnt vmcnt(3)" ::: "memory");
    else             asm volatile("s_waitcnt vmcnt(0)" ::: "memory");
    __builtin_amdgcn_s_barrier();
    asm volatile("" ::: "memory");
    if(kt + 2 < nkt){
      int nb = cur + 2; if(nb >= 3) nb -= 3;
      STAGE128(kt + 2, nb);
    }
    char* cb = sm + cur * 24576;
    s16x8 b[2], a[4];
#pragma unroll
    for(int n = 0; n < 2; ++n) b[n] = *(const s16x8*)(cb + offB[n]);
#pragma unroll
    for(int m = 0; m < 4; ++m) a[m] = *(const s16x8*)(cb + offA[m]);
    __builtin_amdgcn_s_setprio(1);
#pragma unroll
    for(int m = 0; m < 4; ++m)
#pragma unroll
      for(int n = 0; n < 2; ++n)
        acc[m][n] = __builtin_amdgcn_mfma_f32_16x16x32_bf16(a[m], b[n], acc[m][n], 0, 0, 0);
    __builtin_amdgcn_s_setprio(0);
#pragma unroll
    for(int m = 0; m < 4; ++m) a[m] = *(const s16x8*)(cb + offA[m + 4]);
    __builtin_amdgcn_s_setprio(1);
#pragma unroll
    for(int m = 0; m < 4; ++m)
#pragma unroll
      for(int n = 0; n < 2; ++n)
        acc[m + 4][n] = __builtin_amdgcn_mfma_f32_16x16x32_bf16(a[m], b[n], acc[m + 4][n], 0, 0, 0);
    __builtin_amdgcn_s_setprio(0);
    if(++cur == 3) cur = 0;
  }
#undef STAGE128

  float bvv[2];
#pragma unroll
  for(int n = 0; n < 2; ++n) bvv[n] = bias[bcol + wc * 32 + n * 16 + l15];
#pragma unroll
  for(int m = 0; m < 8; ++m)
#pragma unroll
    for(int n = 0; n < 2; ++n)
#pragma unroll
      for(int r = 0; r < 4; ++r){
        const int row = brow + wr * 128 + m * 16 + (l4 << 2) + r;
        const int col = bcol + wc * 32 + n * 16 + l15;
        C[(size_t)row * ldc + col] = acc[m][n][r] + bvv[n];
      }
}

// ---------- kernel 4a: global attention scores (parallel: 64 blocks) ----------
__global__ __launch_bounds__(256) void gscore_kernel(
    const u16* __restrict__ QKV, float* __restrict__ gpr)
{
  __shared__ float sc[16];
  const int b = blockIdx.x >> 4, i = blockIdx.x & 15;
  const int tid = threadIdx.x;
  const int j = tid >> 4, slice = tid & 15;
  const u16* qp = QKV + (size_t)(b * 16 + i) * 256 * NQKV + slice * 64;
  const u16* kp = QKV + (size_t)(b * 16 + j) * 256 * NQKV + 1024 + slice * 64;
  float acc = 0.f;
#pragma unroll
  for(int c = 0; c < 8; ++c){
    s16x8 qv = *(const s16x8*)(qp + c * 8);
    s16x8 kv = *(const s16x8*)(kp + c * 8);
#pragma unroll
    for(int e = 0; e < 8; ++e) acc += bf2f((u16)qv[e]) * bf2f((u16)kv[e]);
  }
#pragma unroll
  for(int off = 8; off >= 1; off >>= 1) acc += __shfl_xor(acc, off, 64);
  if(slice == 0) sc[j] = acc * 0.125f;
  __syncthreads();
  if(tid < 16){
    float v = sc[tid];
    float m = v;
#pragma unroll
    for(int off = 8; off >= 1; off >>= 1) m = fmaxf(m, __shfl_xor(m, off, 64));
    float p = __expf(v - m);
    float s = p;
#pragma unroll
    for(int off = 8; off >= 1; off >>= 1) s += __shfl_xor(s, off, 64);
    gpr[(size_t)b * 256 + i * 16 + tid] = p / s;
  }
}

// ---------- kernel 4b: global attention PV (reads V from Vt; 64 blocks) ----------
__global__ __launch_bounds__(256) void gpv_kernel(
    const u16* __restrict__ Vt, const float* __restrict__ gpr,
    float* __restrict__ gout)
{
  __shared__ float spr[256];
  const int b = blockIdx.x >> 4, ch = blockIdx.x & 15;
  const int tid = threadIdx.x;
  spr[tid] = gpr[(size_t)b * 256 + tid];
  __syncthreads();
  const int e = (ch << 6) + (tid & 63);
  const int ng = tid >> 6;
  const u16* vp = Vt + (size_t)(b * 16) * 262144 + (size_t)e * 256;
  float o0 = 0.f, o1 = 0.f, o2 = 0.f, o3 = 0.f;
#pragma unroll
  for(int m = 0; m < 16; ++m){
    float v = bf2f(vp[(size_t)m * 262144]);
    o0 += spr[(ng * 4 + 0) * 16 + m] * v;
    o1 += spr[(ng * 4 + 1) * 16 + m] * v;
    o2 += spr[(ng * 4 + 2) * 16 + m] * v;
    o3 += spr[(ng * 4 + 3) * 16 + m] * v;
  }
  gout[((size_t)b * 16 + ng * 4 + 0) * 1024 + e] = o0;
  gout[((size_t)b * 16 + ng * 4 + 1) * 1024 + e] = o1;
  gout[((size_t)b * 16 + ng * 4 + 2) * 1024 + e] = o2;
  gout[((size_t)b * 16 + ng * 4 + 3) * 1024 + e] = o3;
}

// ---------- kernel 5: fused local attention (v3: mini-GEMM pipeline, R11) ----------
__global__ __launch_bounds__(512, 2) void attn_local_kernel(
    const u16* __restrict__ QKV, const u16* __restrict__ Vt,
    const float* __restrict__ gout, u16* __restrict__ AO)
{
  __shared__ char sm[131072];
  float* smax = (float*)(sm + 32768);
  float* ssum = (float*)(sm + 33792);
  const int tid = threadIdx.x;
  const int wv = tid >> 6, lane = tid & 63;
  const int l15 = lane & 15, l4 = lane >> 4;
  const int wr = wv >> 2, wc = wv & 3;
  int bid = (int)blockIdx.x;
  bid = (bid & 7) * 32 + (bid >> 3);
  const int seg = bid >> 2, rt = bid & 3;
  const int r0 = rt << 6;
  const size_t segQ = (size_t)seg * 256 * NQKV;

  const int offq = wv * 1024 + lane * 16;
  const int dstQ = wv * 1024;
  const int qrow = offq >> 7;
  const int qgs  = ((offq >> 4) & 7) ^ (qrow & 7);
  const u16* qsrc = QKV + segQ + (size_t)(r0 + qrow) * NQKV + qgs * 8;
  const u16* ksrc[4];
  const u16* vsrc[4];
#pragma unroll
  for(int c = 0; c < 4; ++c){
    int off = c * 8192 + offq;
    int row = off >> 7;
    int gs  = ((off >> 4) & 7) ^ (row & 7);
    ksrc[c] = QKV + segQ + (size_t)row * NQKV + 1024 + gs * 8;
    vsrc[c] = Vt + (size_t)seg * 262144 + (size_t)row * 256 + gs * 8;
  }

#define STAGE_P1(d0_, base_) do{                                        \
    gl_lds16(qsrc + (d0_), sm + (base_) + dstQ);                        \
    _Pragma("unroll")                                                   \
    for(int c_ = 0; c_ < 4; ++c_)                                       \
      gl_lds16(ksrc[c_] + (d0_), sm + (base_) + 8192 + c_ * 8192 + dstQ); \
  }while(0)
#define STAGE_V(j_, vb_) do{                                            \
    const int vo_ = ((j_) >> 2) * 65536 + ((j_) & 3) * 64;              \
    _Pragma("unroll")                                                   \
    for(int c_ = 0; c_ < 4; ++c_)                                       \
      gl_lds16(vsrc[c_] + vo_, sm + 32768 + (vb_) * 32768 + c_ * 8192 + dstQ); \
  }while(0)

  int aOff[2][2], bOff[4][2];
#pragma unroll
  for(int m = 0; m < 2; ++m){
    int row = wr * 32 + m * 16 + l15;
#pragma unroll
    for(int kk = 0; kk < 2; ++kk)
      aOff[m][kk] = row * 128 + ((kk * 64 + l4 * 16) ^ ((row & 7) << 4));
  }
#pragma unroll
  for(int n = 0; n < 4; ++n){
    int row = wc * 64 + n * 16 + l15;
#pragma unroll
    for(int kk = 0; kk < 2; ++kk)
      bOff[n][kk] = 8192 + row * 128 + ((kk * 64 + l4 * 16) ^ ((row & 7) << 4));
  }

  const f32x4 fz = {0.f, 0.f, 0.f, 0.f};
  f32x4 acc1[2][4];
#pragma unroll
  for(int m = 0; m < 2; ++m)
#pragma unroll
    for(int n = 0; n < 4; ++n) acc1[m][n] = fz;

  STAGE_P1(0, 0); STAGE_P1(64, 40960);
  asm volatile("s_waitcnt vmcnt(5)" ::: "memory");
  __builtin_amdgcn_s_barrier();
  asm volatile("" ::: "memory");
  int cur = 0;
  for(int dt = 0; dt < 16; ++dt){
    const int base = cur * 40960;
    if(dt + 2 < 16){
      int nb = cur + 2; if(nb >= 3) nb -= 3;
      STAGE_P1((dt + 2) << 6, nb * 40960);
    }
    s16x8 a[2][2], b[4][2];
#pragma unroll
    for(int m = 0; m < 2; ++m)
#pragma unroll
      for(int kk = 0; kk < 2; ++kk) a[m][kk] = *(const s16x8*)(sm + base + aOff[m][kk]);
#pragma unroll
    for(int n = 0; n < 4; ++n)
#pragma unroll
      for(int kk = 0; kk < 2; ++kk) b[n][kk] = *(const s16x8*)(sm + base + bOff[n][kk]);
    __builtin_amdgcn_s_setprio(1);
#pragma unroll
    for(int kk = 0; kk < 2; ++kk)
#pragma unroll
      for(int m = 0; m < 2; ++m)
#pragma unroll
        for(int n = 0; n < 4; ++n)
          acc1[m][n] = __builtin_amdgcn_mfma_f32_16x16x32_bf16(a[m][kk], b[n][kk], acc1[m][n], 0, 0, 0);
    __builtin_amdgcn_s_setprio(0);
    if(dt + 2 < 16) asm volatile("s_waitcnt vmcnt(5) lgkmcnt(0)" ::: "memory");
    else            asm volatile("s_waitcnt vmcnt(0) lgkmcnt(0)" ::: "memory");
    __builtin_amdgcn_s_barrier();
    asm volatile("" ::: "memory");
    if(++cur == 3) cur = 0;
  }

  const float CE = 0.18033688011112042f;   // SCALE * log2(e)
#pragma unroll
  for(int m = 0; m < 2; ++m)
#pragma unroll
    for(int r = 0; r < 4; ++r){
      float v = -1e30f;
#pragma unroll
      for(int n = 0; n < 4; ++n) v = fmaxf(v, acc1[m][n][r]);
#pragma unroll
      for(int off = 8; off >= 1; off >>= 1) v = fmaxf(v, __shfl_xor(v, off, 64));
      if(l15 == 0) smax[wc * 64 + wr * 32 + m * 16 + (l4 << 2) + r] = v;
    }
  asm volatile("s_waitcnt lgkmcnt(0)" ::: "memory");
  __builtin_amdgcn_s_barrier();
  asm volatile("" ::: "memory");
#pragma unroll
  for(int m = 0; m < 2; ++m)
#pragma unroll
    for(int r = 0; r < 4; ++r){
      const int idx = wr * 32 + m * 16 + (l4 << 2) + r;
      const float g = fmaxf(fmaxf(smax[idx], smax[64 + idx]),
                            fmaxf(smax[128 + idx], smax[192 + idx]));
      float s = 0.f;
#pragma unroll
      for(int n = 0; n < 4; ++n){
        float p = exp2f((acc1[m][n][r] - g) * CE);
        acc1[m][n][r] = p;
        s += p;
      }
#pragma unroll
      for(int off = 8; off >= 1; off >>= 1) s += __shfl_xor(s, off, 64);
      if(l15 == 0) ssum[wc * 64 + idx] = s;
    }
  asm volatile("s_waitcnt lgkmcnt(0)" ::: "memory");
  __builtin_amdgcn_s_barrier();
  asm volatile("" ::: "memory");
  float inv2[2][4];
#pragma unroll
  for(int m = 0; m < 2; ++m)
#pragma unroll
    for(int r = 0; r < 4; ++r){
      const int idx = wr * 32 + m * 16 + (l4 << 2) + r;
      inv2[m][r] = 1.f / (ssum[idx] + ssum[64 + idx] + ssum[128 + idx] + ssum[192 + idx]);
    }
#pragma unroll
  for(int m = 0; m < 2; ++m)
#pragma unroll
    for(int n = 0; n < 4; ++n)
#pragma unroll
      for(int r = 0; r < 4; ++r){
        const int rr = wr * 32 + m * 16 + (l4 << 2) + r;
        const int t  = wc * 64 + n * 16 + l15;
        *(u16*)(sm + rr * 512 + ((t << 1) ^ ((rr & 7) << 4))) = f2bf(acc1[m][n][r] * inv2[m][r]);
      }
  asm volatile("s_waitcnt lgkmcnt(0)" ::: "memory");
  __builtin_amdgcn_s_barrier();
  asm volatile("" ::: "memory");

  int prow[2], pswz[2];
#pragma unroll
  for(int m = 0; m < 2; ++m){
    int row = wr * 32 + m * 16 + l15;
    prow[m] = row * 512;
    pswz[m] = (row & 7) << 4;
  }
  int vOff[4][2];
#pragma unroll
  for(int n = 0; n < 4; ++n){
    int row = wc * 64 + n * 16 + l15;
#pragma unroll
    for(int kk = 0; kk < 2; ++kk)
      vOff[n][kk] = row * 128 + ((kk * 64 + l4 * 16) ^ ((row & 7) << 4));
  }

  STAGE_V(0, 0); STAGE_V(1, 1);
  asm volatile("s_waitcnt vmcnt(4)" ::: "memory");
  __builtin_amdgcn_s_barrier();
  asm volatile("" ::: "memory");
  f32x4 acc2[2][4];
  int cv = 0;
  for(int j = 0; j < 16; ++j){
    const int ts = j & 3, ns = j >> 2;
    if(ts == 0){
#pragma unroll
      for(int m = 0; m < 2; ++m)
#pragma unroll
        for(int n = 0; n < 4; ++n) acc2[m][n] = fz;
    }
    if(j + 2 < 16){
      int nb = cv + 2; if(nb >= 3) nb -= 3;
      STAGE_V(j + 2, nb);
    }
    char* vbase = sm + 32768 + cv * 32768;
    s16x8 a[2][2], b[4][2];
#pragma unroll
    for(int m = 0; m < 2; ++m)
#pragma unroll
      for(int kk = 0; kk < 2; ++kk)
        a[m][kk] = *(const s16x8*)(sm + prow[m] + (((ts << 7) + (kk << 6) + (l4 << 4)) ^ pswz[m]));
#pragma unroll
    for(int n = 0; n < 4; ++n)
#pragma unroll
      for(int kk = 0; kk < 2; ++kk) b[n][kk] = *(const s16x8*)(vbase + vOff[n][kk]);
    __builtin_amdgcn_s_setprio(1);
#pragma unroll
    for(int kk = 0; kk < 2; ++kk)
#pragma unroll
      for(int m = 0; m < 2; ++m)
#pragma unroll
        for(int n = 0; n < 4; ++n)
          acc2[m][n] = __builtin_amdgcn_mfma_f32_16x16x32_bf16(a[m][kk], b[n][kk], acc2[m][n], 0, 0, 0);
    __builtin_amdgcn_s_setprio(0);
    if(j + 2 < 16) asm volatile("s_waitcnt vmcnt(4) lgkmcnt(0)" ::: "memory");
    else           asm volatile("s_waitcnt vmcnt(0) lgkmcnt(0)" ::: "memory");
    __builtin_amdgcn_s_barrier();
    asm volatile("" ::: "memory");
    if(++cv == 3) cv = 0;

    if(ts == 3){
      float gv[4];
#pragma unroll
      for(int n = 0; n < 4; ++n)
        gv[n] = gout[(size_t)seg * 1024 + ns * 256 + wc * 64 + n * 16 + l15];
#pragma unroll
      for(int m = 0; m < 2; ++m)
#pragma unroll
        for(int n = 0; n < 4; ++n)
#pragma unroll
          for(int r = 0; r < 4; ++r){
            const int row = r0 + wr * 32 + m * 16 + (l4 << 2) + r;
            const int e   = ns * 256 + wc * 64 + n * 16 + l15;
            AO[((size_t)seg * 256 + row) * 1024 + e] = f2bf(acc2[m][n][r] + gv[n]);
          }
    }
  }
#undef STAGE_P1
#undef STAGE_V
}

// ---------- launch ----------
extern "C" void kernel_launch(void* const* d_in, const int* in_sizes, int n_in,
                              void* d_out, int out_size, void* d_ws, size_t ws_size,
                              hipStream_t stream)
{
  const float* x  = (const float*)d_in[0];
  const float* Wq = (const float*)d_in[1];
  const float* bq = (const float*)d_in[2];
  const float* Wk = (const float*)d_in[3];
  const float* bk = (const float*)d_in[4];
  const float* Wv = (const float*)d_in[5];
  const float* bv = (const float*)d_in[6];
  const float* Wo = (const float*)d_in[7];
  const float* bo = (const float*)d_in[8];

  char* ws = (char*)d_ws;
  u16*   xb    = (u16*)(ws + O_XB);
  u16*   wqkvb = (u16*)(ws + O_WQKV);
  u16*   wob   = (u16*)(ws + O_WO);
  float* bqkv  = (float*)(ws + O_BQKV);
  u16*   qkv   = (u16*)(ws + O_QKV);
  u16*   vt    = (u16*)(ws + O_VT);
  float* gout  = (float*)(ws + O_GOUT);
  float* gpr   = (float*)(ws + O_GPR);
  u16*   ao    = xb;   // alias: xb dead after QKV GEMM

  pack_kernel<<<4096, 256, 0, stream>>>(x, Wq, Wk, Wv, Wo, bq, bk, bv, xb, wqkvb, wob, bqkv);
  gemm256_kernel<<<dim3((NQKV / 256) * (MROWS / 256)), 512, 0, stream>>>(
      xb, wqkvb, bqkv, qkv, vt, DMODEL, NQKV, NQKV / 256);
  gscore_kernel<<<64, 256, 0, stream>>>(qkv, gpr);
  gpv_kernel<<<64, 256, 0, stream>>>(vt, gpr, gout);
  attn_local_kernel<<<256, 512, 0, stream>>>(qkv, vt, gout, ao);
  gemm128_kernel<<<dim3((DMODEL / 128) * (MROWS / 256)), 512, 0, stream>>>(
      ao, wob, bo, (float*)d_out, DMODEL, DMODEL, DMODEL / 128);
}